// Round 4
// baseline (627.207 us; speedup 1.0000x reference)
//
#include <hip/hip_runtime.h>

#define NVOX 500000
#define CIN 32
#define COUT 64
#define KK 27
#define EPSV 1e-5f

typedef __bf16 bf16x8 __attribute__((ext_vector_type(8)));
typedef float f32x4 __attribute__((ext_vector_type(4)));

#define MFMA16 __builtin_amdgcn_mfma_f32_16x16x32_bf16

__device__ __forceinline__ float bf2f(ushort u) {
    return __uint_as_float(((unsigned)u) << 16);
}
__device__ __forceinline__ ushort f2bf(float f) {
    unsigned u = __float_as_uint(f);
    unsigned r = (u + 0x7FFFu + ((u >> 16) & 1u)) >> 16;  // RNE
    return (ushort)r;
}
union U4BF { uint4 u; bf16x8 b; ushort s[8]; };
__device__ __forceinline__ bf16x8 as_bf8(uint4 v) { U4BF c; c.u = v; return c.b; }
__device__ __forceinline__ bf16x8 f8_to_bf8(float4 a, float4 b) {
    U4BF c;
    c.s[0] = f2bf(a.x); c.s[1] = f2bf(a.y); c.s[2] = f2bf(a.z); c.s[3] = f2bf(a.w);
    c.s[4] = f2bf(b.x); c.s[5] = f2bf(b.y); c.s[6] = f2bf(b.z); c.s[7] = f2bf(b.w);
    return c.b;
}

__device__ __forceinline__ float4 ldv4(const float4* p, long long i) { return p[i]; }
__device__ __forceinline__ float4 ldv4(const ushort4* p, long long i) {
    ushort4 u = p[i];
    return make_float4(bf2f(u.x), bf2f(u.y), bf2f(u.z), bf2f(u.w));
}

// ---------------- prep: zero stats + sentinel rows, swizzle weights (f32 -> bf16 frags) ----
__global__ void prep_kernel(const float* __restrict__ W1, const float* __restrict__ W2,
                            const float* __restrict__ Wres,
                            ushort* __restrict__ w1s, ushort* __restrict__ w2s,
                            ushort* __restrict__ wrs,
                            float* __restrict__ stats,
                            ushort* __restrict__ y1, ushort* __restrict__ y2) {
    int t = blockIdx.x * 256 + threadIdx.x;
    if (t < 192) { stats[t] = 0.f; return; }
    if (t < 224) { y1[(size_t)NVOX * CIN + (t - 192)] = 0; return; }
    if (t < 288) { y2[(size_t)NVOX * COUT + (t - 224)] = 0; return; }
    int d = t - 288;
    if (d < 27 * 4 * 64 * 8) {  // 55296
        int j = d & 7, lane = (d >> 3) & 63, nt = (d >> 9) & 3, k = d >> 11;
        int ci = ((lane >> 4) << 3) + j, co = (nt << 4) + (lane & 15);
        w1s[d] = f2bf(W1[(k * CIN + ci) * COUT + co]);
        return;
    }
    d -= 27 * 4 * 64 * 8;
    if (d < 27 * 2 * 4 * 64 * 8) {  // 110592
        int j = d & 7, lane = (d >> 3) & 63, nt = (d >> 9) & 3, half = (d >> 11) & 1, k = d >> 12;
        int ci = (half << 5) + ((lane >> 4) << 3) + j, co = (nt << 4) + (lane & 15);
        w2s[d] = f2bf(W2[(k * COUT + ci) * COUT + co]);
        return;
    }
    d -= 27 * 2 * 4 * 64 * 8;
    if (d < 4 * 64 * 8) {  // 2048
        int j = d & 7, lane = (d >> 3) & 63, nt = (d >> 9) & 3;
        int ci = ((lane >> 4) << 3) + j, co = (nt << 4) + (lane & 15);
        wrs[d] = f2bf(Wres[ci * COUT + co]);
    }
}

// ---------------- per-channel sum/sumsq, x4 vectorized ----------------
template <int C, typename T4>
__global__ void stats_kernel(const T4* __restrict__ in, long long total4,
                             float* __restrict__ gsum, float* __restrict__ gsq) {
    __shared__ float s_sum[C];
    __shared__ float s_sq[C];
    int t = threadIdx.x;
    if (t < C) { s_sum[t] = 0.f; s_sq[t] = 0.f; }
    __syncthreads();
    long long i0 = (long long)blockIdx.x * blockDim.x + t;
    long long stride = (long long)gridDim.x * blockDim.x;  // stride*4 multiple of C
    int c0 = (int)((i0 * 4) & (C - 1));
    float ls0 = 0.f, ls1 = 0.f, ls2 = 0.f, ls3 = 0.f;
    float lq0 = 0.f, lq1 = 0.f, lq2 = 0.f, lq3 = 0.f;
    for (long long i = i0; i < total4; i += stride) {
        float4 v = ldv4(in, i);
        ls0 += v.x; lq0 += v.x * v.x;
        ls1 += v.y; lq1 += v.y * v.y;
        ls2 += v.z; lq2 += v.z * v.z;
        ls3 += v.w; lq3 += v.w * v.w;
    }
    atomicAdd(&s_sum[c0 + 0], ls0); atomicAdd(&s_sq[c0 + 0], lq0);
    atomicAdd(&s_sum[c0 + 1], ls1); atomicAdd(&s_sq[c0 + 1], lq1);
    atomicAdd(&s_sum[c0 + 2], ls2); atomicAdd(&s_sq[c0 + 2], lq2);
    atomicAdd(&s_sum[c0 + 3], ls3); atomicAdd(&s_sq[c0 + 3], lq3);
    __syncthreads();
    if (t < C) {
        atomicAdd(&gsum[t], s_sum[t]);
        atomicAdd(&gsq[t], s_sq[t]);
    }
}

// ---------------- y = relu(bn(x)), x4 vectorized, bf16 out ----------------
template <int C, typename T4>
__global__ void bn_relu_kernel(const T4* __restrict__ in, ushort4* __restrict__ out,
                               long long total4,
                               const float* __restrict__ gsum, const float* __restrict__ gsq,
                               const float* __restrict__ gamma, const float* __restrict__ beta,
                               float invN) {
    long long i0 = (long long)blockIdx.x * blockDim.x + threadIdx.x;
    long long stride = (long long)gridDim.x * blockDim.x;
    int c0 = (int)((i0 * 4) & (C - 1));
    float a[4], bb[4];
#pragma unroll
    for (int j = 0; j < 4; j++) {
        int c = c0 + j;
        float m = gsum[c] * invN;
        float v = fmaxf(gsq[c] * invN - m * m, 0.f);
        a[j] = gamma[c] * rsqrtf(v + EPSV);
        bb[j] = beta[c] - m * a[j];
    }
    for (long long i = i0; i < total4; i += stride) {
        float4 v = ldv4(in, i);
        ushort4 o;
        o.x = f2bf(fmaxf(v.x * a[0] + bb[0], 0.f));
        o.y = f2bf(fmaxf(v.y * a[1] + bb[1], 0.f));
        o.z = f2bf(fmaxf(v.z * a[2] + bb[2], 0.f));
        o.w = f2bf(fmaxf(v.w * a[3] + bb[3], 0.f));
        out[i] = o;
    }
}

// ---------------- conv1: [N,32] -> [N,64], 48 rows/wave, barrier-free, fused stats -------
// No in-loop barrier: weights are L1/L2-hot (every wave on a CU streams the same 108 KB),
// loaded per-iter straight to registers (single set, no ping-pong -> no spill).
// Gathers depth-2 register-prefetched, next-idx one iter ahead; sched_barrier(0) pins
// the refill block so the scheduler can't sink it to point-of-use.
// VGPR budget: acc 48 + ga 24 + wb 16 + misc ~15 ~= 103 < 128 (4 waves/SIMD).
__global__ __launch_bounds__(256, 4) void conv1_kernel(const ushort* __restrict__ y1,
                                                       const int* __restrict__ nbr,
                                                       const ushort* __restrict__ w1s,
                                                       ushort* __restrict__ out1,
                                                       float* __restrict__ gsum,
                                                       float* __restrict__ gsq) {
    __shared__ int s_idx[192 * KK];       // 20736 B
    __shared__ float s_sum[COUT], s_sq[COUT];
    const int tid = threadIdx.x;
    const int lane = tid & 63, wv = tid >> 6;
    const int m = lane & 15, g = lane >> 4;
    if (tid < COUT) { s_sum[tid] = 0.f; s_sq[tid] = 0.f; }

    const int blockRow0 = blockIdx.x * 192;
    const int gbase = blockRow0 * KK;
    const int glim = NVOX * KK;
    for (int i = tid; i < 192 * KK; i += 256) {
        int gi = gbase + i;
        int v = (gi < glim) ? nbr[gi] : NVOX;
        s_idx[i] = (int)min((unsigned)v, (unsigned)NVOX);
    }
    __syncthreads();

    const uint4* __restrict__ yv = (const uint4*)y1;
    const uint4* __restrict__ w1v = (const uint4*)w1s;
    const int ib[3] = {(wv * 48 + m) * KK, (wv * 48 + 16 + m) * KK, (wv * 48 + 32 + m) * KK};

    // prologue: gathers for k=0 (slot0) and k=1 (slot1); ni = idx for k=2
    uint4 ga[3][2];
    int ni[3];
#pragma unroll
    for (int p = 0; p < 2; p++)
#pragma unroll
        for (int t = 0; t < 3; t++) ga[t][p] = yv[s_idx[ib[t] + p] * 4 + g];
#pragma unroll
    for (int t = 0; t < 3; t++) ni[t] = s_idx[ib[t] + 2];

    f32x4 acc[3][4];
#pragma unroll
    for (int t = 0; t < 3; t++)
#pragma unroll
        for (int nt = 0; nt < 4; nt++) acc[t][nt] = (f32x4){0.f, 0.f, 0.f, 0.f};

#pragma unroll
    for (int k = 0; k < KK; k++) {
        const int b = k & 1;
        // current-k weight fragments (L1-hot, shared by all waves on the CU)
        uint4 wb0 = w1v[(k * 4 + 0) * 64 + lane];
        uint4 wb1 = w1v[(k * 4 + 1) * 64 + lane];
        uint4 wb2 = w1v[(k * 4 + 2) * 64 + lane];
        uint4 wb3 = w1v[(k * 4 + 3) * 64 + lane];
        __builtin_amdgcn_s_setprio(1);
#pragma unroll
        for (int t = 0; t < 3; t++) {
            bf16x8 a = as_bf8(ga[t][b]);
            acc[t][0] = MFMA16(a, as_bf8(wb0), acc[t][0], 0, 0, 0);
            acc[t][1] = MFMA16(a, as_bf8(wb1), acc[t][1], 0, 0, 0);
            acc[t][2] = MFMA16(a, as_bf8(wb2), acc[t][2], 0, 0, 0);
            acc[t][3] = MFMA16(a, as_bf8(wb3), acc[t][3], 0, 0, 0);
        }
        __builtin_amdgcn_s_setprio(0);
        __builtin_amdgcn_sched_barrier(0);
        if (k + 2 < KK) {                 // refill freed slot with k+2's rows
#pragma unroll
            for (int t = 0; t < 3; t++) ga[t][b] = yv[ni[t] * 4 + g];
            if (k + 3 < KK) {
#pragma unroll
                for (int t = 0; t < 3; t++) ni[t] = s_idx[ib[t] + k + 3];
            }
        }
        __builtin_amdgcn_sched_barrier(0);
    }

    // epilogue: store bf16 pre-BN output
#pragma unroll
    for (int t = 0; t < 3; t++) {
        int rbase = blockRow0 + wv * 48 + t * 16 + g * 4;
#pragma unroll
        for (int reg = 0; reg < 4; reg++) {
            int r = rbase + reg;
            if (r < NVOX) {
                size_t bo = (size_t)r * COUT + m;
                out1[bo] = f2bf(acc[t][0][reg]);
                out1[bo + 16] = f2bf(acc[t][1][reg]);
                out1[bo + 32] = f2bf(acc[t][2][reg]);
                out1[bo + 48] = f2bf(acc[t][3][reg]);
            }
        }
    }

    // fused BN stats (f32, pre-rounding; OOB rows contribute exact zeros)
#pragma unroll
    for (int nt = 0; nt < 4; nt++) {
        float s = 0.f, q = 0.f;
#pragma unroll
        for (int t = 0; t < 3; t++)
#pragma unroll
            for (int reg = 0; reg < 4; reg++) {
                float v = acc[t][nt][reg];
                s += v; q += v * v;
            }
        s += __shfl_xor(s, 16); q += __shfl_xor(q, 16);
        s += __shfl_xor(s, 32); q += __shfl_xor(q, 32);
        if (g == 0) { atomicAdd(&s_sum[nt * 16 + m], s); atomicAdd(&s_sq[nt * 16 + m], q); }
    }
    __syncthreads();
    if (tid < COUT) {
        atomicAdd(&gsum[tid], s_sum[tid]);
        atomicAdd(&gsq[tid], s_sq[tid]);
    }
}

// ---------------- conv2: [N,64] -> [N,64] + fused residual, 32 rows/wave, barrier-free ---
// VGPR budget: acc 32 + ga 32 + wb 32 + misc ~15 ~= 111 < 128 (4 waves/SIMD).
__global__ __launch_bounds__(256, 4) void conv2_kernel(const ushort* __restrict__ y2,
                                                       const int* __restrict__ nbr,
                                                       const ushort* __restrict__ w2s,
                                                       const float* __restrict__ x,
                                                       const ushort* __restrict__ wrs,
                                                       const float* __restrict__ bres,
                                                       float* __restrict__ out) {
    __shared__ int s_idx[128 * KK];       // 13824 B
    const int tid = threadIdx.x;
    const int lane = tid & 63, wv = tid >> 6;
    const int m = lane & 15, g = lane >> 4;

    const int blockRow0 = blockIdx.x * 128;
    const int gbase = blockRow0 * KK;
    const int glim = NVOX * KK;
    for (int i = tid; i < 128 * KK; i += 256) {
        int gi = gbase + i;
        int v = (gi < glim) ? nbr[gi] : NVOX;
        s_idx[i] = (int)min((unsigned)v, (unsigned)NVOX);
    }
    __syncthreads();

    const uint4* __restrict__ yv = (const uint4*)y2;
    const uint4* __restrict__ w2v = (const uint4*)w2s;
    const float4* __restrict__ xv = (const float4*)x;
    const uint4* __restrict__ wrv = (const uint4*)wrs;
    const int ib[2] = {(wv * 32 + m) * KK, (wv * 32 + 16 + m) * KK};

    // prologue: gathers for k=0 (slot0) and k=1 (slot1); ni = idx for k=2
    uint4 ga[2][2][2];   // [tile][half][slot]
    int ni[2];
#pragma unroll
    for (int p = 0; p < 2; p++)
#pragma unroll
        for (int t = 0; t < 2; t++) {
            int idx = s_idx[ib[t] + p];
            ga[t][0][p] = yv[idx * 8 + g];
            ga[t][1][p] = yv[idx * 8 + 4 + g];
        }
#pragma unroll
    for (int t = 0; t < 2; t++) ni[t] = s_idx[ib[t] + 2];

    f32x4 acc[2][4];
#pragma unroll
    for (int t = 0; t < 2; t++)
#pragma unroll
        for (int nt = 0; nt < 4; nt++) acc[t][nt] = (f32x4){0.f, 0.f, 0.f, 0.f};

#pragma unroll
    for (int k = 0; k < KK; k++) {
        const int b = k & 1;
        // current-k weight fragments (8 x 16B, L1-hot)
        uint4 wb0 = w2v[(k * 8 + 0) * 64 + lane];
        uint4 wb1 = w2v[(k * 8 + 1) * 64 + lane];
        uint4 wb2 = w2v[(k * 8 + 2) * 64 + lane];
        uint4 wb3 = w2v[(k * 8 + 3) * 64 + lane];
        uint4 wb4 = w2v[(k * 8 + 4) * 64 + lane];
        uint4 wb5 = w2v[(k * 8 + 5) * 64 + lane];
        uint4 wb6 = w2v[(k * 8 + 6) * 64 + lane];
        uint4 wb7 = w2v[(k * 8 + 7) * 64 + lane];
        __builtin_amdgcn_s_setprio(1);
#pragma unroll
        for (int t = 0; t < 2; t++) {
            bf16x8 a0 = as_bf8(ga[t][0][b]);
            bf16x8 a1 = as_bf8(ga[t][1][b]);
            acc[t][0] = MFMA16(a0, as_bf8(wb0), acc[t][0], 0, 0, 0);
            acc[t][1] = MFMA16(a0, as_bf8(wb1), acc[t][1], 0, 0, 0);
            acc[t][2] = MFMA16(a0, as_bf8(wb2), acc[t][2], 0, 0, 0);
            acc[t][3] = MFMA16(a0, as_bf8(wb3), acc[t][3], 0, 0, 0);
            acc[t][0] = MFMA16(a1, as_bf8(wb4), acc[t][0], 0, 0, 0);
            acc[t][1] = MFMA16(a1, as_bf8(wb5), acc[t][1], 0, 0, 0);
            acc[t][2] = MFMA16(a1, as_bf8(wb6), acc[t][2], 0, 0, 0);
            acc[t][3] = MFMA16(a1, as_bf8(wb7), acc[t][3], 0, 0, 0);
        }
        __builtin_amdgcn_s_setprio(0);
        __builtin_amdgcn_sched_barrier(0);
        if (k + 2 < KK) {                 // refill freed slot with k+2's rows
#pragma unroll
            for (int t = 0; t < 2; t++) {
                ga[t][0][b] = yv[ni[t] * 8 + g];
                ga[t][1][b] = yv[ni[t] * 8 + 4 + g];
            }
            if (k + 3 < KK) {
#pragma unroll
                for (int t = 0; t < 2; t++) ni[t] = s_idx[ib[t] + k + 3];
            }
        }
        __builtin_amdgcn_sched_barrier(0);
    }

    // residual GEMM: A = x (f32 -> bf16 on the fly, K=32), B = Wres
    uint4 wr0 = wrv[lane];
    uint4 wr1 = wrv[64 + lane];
    uint4 wr2 = wrv[128 + lane];
    uint4 wr3 = wrv[192 + lane];
#pragma unroll
    for (int t = 0; t < 2; t++) {
        int arow = blockRow0 + wv * 32 + t * 16 + m;
        bf16x8 ar;
        if (arow < NVOX) {
            float4 f0 = xv[(size_t)arow * 8 + g * 2];
            float4 f1 = xv[(size_t)arow * 8 + g * 2 + 1];
            ar = f8_to_bf8(f0, f1);
        } else {
            uint4 zz = {0u, 0u, 0u, 0u};
            ar = as_bf8(zz);
        }
        acc[t][0] = MFMA16(ar, as_bf8(wr0), acc[t][0], 0, 0, 0);
        acc[t][1] = MFMA16(ar, as_bf8(wr1), acc[t][1], 0, 0, 0);
        acc[t][2] = MFMA16(ar, as_bf8(wr2), acc[t][2], 0, 0, 0);
        acc[t][3] = MFMA16(ar, as_bf8(wr3), acc[t][3], 0, 0, 0);
    }

    float br0 = bres[m];
    float br1 = bres[16 + m];
    float br2 = bres[32 + m];
    float br3 = bres[48 + m];
#pragma unroll
    for (int t = 0; t < 2; t++) {
        int rbase = blockRow0 + wv * 32 + t * 16 + g * 4;
#pragma unroll
        for (int reg = 0; reg < 4; reg++) {
            int r = rbase + reg;
            if (r < NVOX) {
                size_t bo = (size_t)r * COUT + m;
                out[bo] = acc[t][0][reg] + br0;
                out[bo + 16] = acc[t][1][reg] + br1;
                out[bo + 32] = acc[t][2][reg] + br2;
                out[bo + 48] = acc[t][3][reg] + br3;
            }
        }
    }
}

extern "C" void kernel_launch(void* const* d_in, const int* in_sizes, int n_in,
                              void* d_out, int out_size, void* d_ws, size_t ws_size,
                              hipStream_t stream) {
    const float* x = (const float*)d_in[0];
    const int* nbr = (const int*)d_in[1];
    const float* W1 = (const float*)d_in[2];
    const float* W2 = (const float*)d_in[3];
    const float* Wres = (const float*)d_in[4];
    const float* bres = (const float*)d_in[5];
    const float* g1 = (const float*)d_in[6];
    const float* b1 = (const float*)d_in[7];
    const float* g2 = (const float*)d_in[8];
    const float* b2 = (const float*)d_in[9];
    float* out = (float*)d_out;

    // Workspace (~97 MB): y1 bf16 32MB, y2 bf16 64MB, weights/stats <0.5MB.
    // conv1's pre-BN bf16 output aliases the first 64MB of d_out (float, 128MB);
    // conv2 rewrites all of d_out afterwards.
    char* ws = (char*)d_ws;
    size_t off = 0;
    auto alloc = [&](size_t bytes) -> void* {
        void* p = ws + off;
        off = (off + bytes + 255) & ~(size_t)255;
        return p;
    };
    ushort* y1 = (ushort*)alloc((size_t)(NVOX + 1) * CIN * 2);    // sentinel row N = zeros
    ushort* y2 = (ushort*)alloc((size_t)(NVOX + 1) * COUT * 2);
    ushort* w1s = (ushort*)alloc(55296 * 2);
    ushort* w2s = (ushort*)alloc(110592 * 2);
    ushort* wrs = (ushort*)alloc(2048 * 2);
    float* stats = (float*)alloc(192 * 4);
    float* sum1 = stats, *sq1 = stats + 32, *sum2 = stats + 64, *sq2 = stats + 128;
    ushort* out1 = (ushort*)d_out;  // bf16 pre-BN conv1 output, first 64MB of d_out

    const float invN = 1.0f / (float)NVOX;
    const long long tot1 = (long long)NVOX * CIN / 4;   // float4/ushort4 groups
    const long long tot2 = (long long)NVOX * COUT / 4;
    const int conv1Grid = (NVOX + 191) / 192;
    const int conv2Grid = (NVOX + 127) / 128;

    hipLaunchKernelGGL(prep_kernel, dim3(658), dim3(256), 0, stream,
                       W1, W2, Wres, w1s, w2s, wrs, stats, y1, y2);
    hipLaunchKernelGGL(HIP_KERNEL_NAME(stats_kernel<32, float4>), dim3(1024), dim3(256), 0, stream,
                       (const float4*)x, tot1, sum1, sq1);
    hipLaunchKernelGGL(HIP_KERNEL_NAME(bn_relu_kernel<32, float4>), dim3(2048), dim3(256), 0, stream,
                       (const float4*)x, (ushort4*)y1, tot1, sum1, sq1, g1, b1, invN);
    hipLaunchKernelGGL(conv1_kernel, dim3(conv1Grid), dim3(256), 0, stream,
                       y1, nbr, w1s, out1, sum2, sq2);
    hipLaunchKernelGGL(HIP_KERNEL_NAME(bn_relu_kernel<64, ushort4>), dim3(2048), dim3(256), 0, stream,
                       (const ushort4*)out1, (ushort4*)y2, tot2, sum2, sq2, g2, b2, invN);
    hipLaunchKernelGGL(conv2_kernel, dim3(conv2Grid), dim3(256), 0, stream,
                       y2, nbr, w2s, x, wrs, bres, out);
    (void)in_sizes; (void)n_in; (void)out_size; (void)ws_size;
}

// Round 5
// 520.412 us; speedup vs baseline: 1.2052x; 1.2052x over previous
//
#include <hip/hip_runtime.h>

#define NVOX 500000
#define CIN 32
#define COUT 64
#define KK 27
#define EPSV 1e-5f

typedef __bf16 bf16x8 __attribute__((ext_vector_type(8)));
typedef float f32x4 __attribute__((ext_vector_type(4)));

#define MFMA16 __builtin_amdgcn_mfma_f32_16x16x32_bf16

__device__ __forceinline__ float bf2f(ushort u) {
    return __uint_as_float(((unsigned)u) << 16);
}
__device__ __forceinline__ ushort f2bf(float f) {
    unsigned u = __float_as_uint(f);
    unsigned r = (u + 0x7FFFu + ((u >> 16) & 1u)) >> 16;  // RNE
    return (ushort)r;
}
union U4BF { uint4 u; bf16x8 b; ushort s[8]; };
__device__ __forceinline__ bf16x8 as_bf8(uint4 v) { U4BF c; c.u = v; return c.b; }
__device__ __forceinline__ bf16x8 f8_to_bf8(float4 a, float4 b) {
    U4BF c;
    c.s[0] = f2bf(a.x); c.s[1] = f2bf(a.y); c.s[2] = f2bf(a.z); c.s[3] = f2bf(a.w);
    c.s[4] = f2bf(b.x); c.s[5] = f2bf(b.y); c.s[6] = f2bf(b.z); c.s[7] = f2bf(b.w);
    return c.b;
}

__device__ __forceinline__ float4 ldv4(const float4* p, long long i) { return p[i]; }
__device__ __forceinline__ float4 ldv4(const ushort4* p, long long i) {
    ushort4 u = p[i];
    return make_float4(bf2f(u.x), bf2f(u.y), bf2f(u.z), bf2f(u.w));
}

// ---------------- prep: zero stats + sentinel rows, swizzle weights (f32 -> bf16 frags) ----
__global__ void prep_kernel(const float* __restrict__ W1, const float* __restrict__ W2,
                            const float* __restrict__ Wres,
                            ushort* __restrict__ w1s, ushort* __restrict__ w2s,
                            ushort* __restrict__ wrs,
                            float* __restrict__ stats,
                            ushort* __restrict__ y1, ushort* __restrict__ y2) {
    int t = blockIdx.x * 256 + threadIdx.x;
    if (t < 192) { stats[t] = 0.f; return; }
    if (t < 224) { y1[(size_t)NVOX * CIN + (t - 192)] = 0; return; }
    if (t < 288) { y2[(size_t)NVOX * COUT + (t - 224)] = 0; return; }
    int d = t - 288;
    if (d < 27 * 4 * 64 * 8) {  // 55296
        int j = d & 7, lane = (d >> 3) & 63, nt = (d >> 9) & 3, k = d >> 11;
        int ci = ((lane >> 4) << 3) + j, co = (nt << 4) + (lane & 15);
        w1s[d] = f2bf(W1[(k * CIN + ci) * COUT + co]);
        return;
    }
    d -= 27 * 4 * 64 * 8;
    if (d < 27 * 2 * 4 * 64 * 8) {  // 110592
        int j = d & 7, lane = (d >> 3) & 63, nt = (d >> 9) & 3, half = (d >> 11) & 1, k = d >> 12;
        int ci = (half << 5) + ((lane >> 4) << 3) + j, co = (nt << 4) + (lane & 15);
        w2s[d] = f2bf(W2[(k * COUT + ci) * COUT + co]);
        return;
    }
    d -= 27 * 2 * 4 * 64 * 8;
    if (d < 4 * 64 * 8) {  // 2048
        int j = d & 7, lane = (d >> 3) & 63, nt = (d >> 9) & 3;
        int ci = ((lane >> 4) << 3) + j, co = (nt << 4) + (lane & 15);
        wrs[d] = f2bf(Wres[ci * COUT + co]);
    }
}

// ---------------- per-channel sum/sumsq, x4 vectorized ----------------
template <int C, typename T4>
__global__ void stats_kernel(const T4* __restrict__ in, long long total4,
                             float* __restrict__ gsum, float* __restrict__ gsq) {
    __shared__ float s_sum[C];
    __shared__ float s_sq[C];
    int t = threadIdx.x;
    if (t < C) { s_sum[t] = 0.f; s_sq[t] = 0.f; }
    __syncthreads();
    long long i0 = (long long)blockIdx.x * blockDim.x + t;
    long long stride = (long long)gridDim.x * blockDim.x;  // stride*4 multiple of C
    int c0 = (int)((i0 * 4) & (C - 1));
    float ls0 = 0.f, ls1 = 0.f, ls2 = 0.f, ls3 = 0.f;
    float lq0 = 0.f, lq1 = 0.f, lq2 = 0.f, lq3 = 0.f;
    for (long long i = i0; i < total4; i += stride) {
        float4 v = ldv4(in, i);
        ls0 += v.x; lq0 += v.x * v.x;
        ls1 += v.y; lq1 += v.y * v.y;
        ls2 += v.z; lq2 += v.z * v.z;
        ls3 += v.w; lq3 += v.w * v.w;
    }
    atomicAdd(&s_sum[c0 + 0], ls0); atomicAdd(&s_sq[c0 + 0], lq0);
    atomicAdd(&s_sum[c0 + 1], ls1); atomicAdd(&s_sq[c0 + 1], lq1);
    atomicAdd(&s_sum[c0 + 2], ls2); atomicAdd(&s_sq[c0 + 2], lq2);
    atomicAdd(&s_sum[c0 + 3], ls3); atomicAdd(&s_sq[c0 + 3], lq3);
    __syncthreads();
    if (t < C) {
        atomicAdd(&gsum[t], s_sum[t]);
        atomicAdd(&gsq[t], s_sq[t]);
    }
}

// ---------------- y = relu(bn(x)), x4 vectorized, bf16 out ----------------
template <int C, typename T4>
__global__ void bn_relu_kernel(const T4* __restrict__ in, ushort4* __restrict__ out,
                               long long total4,
                               const float* __restrict__ gsum, const float* __restrict__ gsq,
                               const float* __restrict__ gamma, const float* __restrict__ beta,
                               float invN) {
    long long i0 = (long long)blockIdx.x * blockDim.x + threadIdx.x;
    long long stride = (long long)gridDim.x * blockDim.x;
    int c0 = (int)((i0 * 4) & (C - 1));
    float a[4], bb[4];
#pragma unroll
    for (int j = 0; j < 4; j++) {
        int c = c0 + j;
        float m = gsum[c] * invN;
        float v = fmaxf(gsq[c] * invN - m * m, 0.f);
        a[j] = gamma[c] * rsqrtf(v + EPSV);
        bb[j] = beta[c] - m * a[j];
    }
    for (long long i = i0; i < total4; i += stride) {
        float4 v = ldv4(in, i);
        ushort4 o;
        o.x = f2bf(fmaxf(v.x * a[0] + bb[0], 0.f));
        o.y = f2bf(fmaxf(v.y * a[1] + bb[1], 0.f));
        o.z = f2bf(fmaxf(v.z * a[2] + bb[2], 0.f));
        o.w = f2bf(fmaxf(v.w * a[3] + bb[3], 0.f));
        out[i] = o;
    }
}

// ---------------- conv1: [N,32] -> [N,64], 48 rows/wave, LDS weight dbuf, fused stats ----
// Weights: LDS double-buffer (lgkm counter, decoupled from gather vmcnt FIFO) with
// 2-deep register staging: weight load for k+2 issued at iter-k top; its ds_write at
// iter k+1 is then OLDER than the newest gather refill, so the compiler's counted
// vmcnt wait for it keeps the in-flight gather slot alive. ds_write placed BEFORE
// the refill. Raw s_barrier + lgkmcnt(0) only — vmcnt is never drained in-loop.
// VGPR budget ~63 + 48 acc(AGPR) = 111 < 128 (4 waves/SIMD).
__global__ __launch_bounds__(256, 4) void conv1_kernel(const ushort* __restrict__ y1,
                                                       const int* __restrict__ nbr,
                                                       const ushort* __restrict__ w1s,
                                                       ushort* __restrict__ out1,
                                                       float* __restrict__ gsum,
                                                       float* __restrict__ gsq) {
    __shared__ int s_idx[192 * KK];       // 20736 B
    __shared__ uint4 swb[2][256];         // 8192 B: 4KB per k, double-buffered
    __shared__ float s_sum[COUT], s_sq[COUT];
    const int tid = threadIdx.x;
    const int lane = tid & 63, wv = tid >> 6;
    const int m = lane & 15, g = lane >> 4;
    if (tid < COUT) { s_sum[tid] = 0.f; s_sq[tid] = 0.f; }

    const int blockRow0 = blockIdx.x * 192;
    const int gbase = blockRow0 * KK;
    const int glim = NVOX * KK;
    for (int i = tid; i < 192 * KK; i += 256) {
        int gi = gbase + i;
        int v = (gi < glim) ? nbr[gi] : NVOX;
        s_idx[i] = (int)min((unsigned)v, (unsigned)NVOX);
    }
    const uint4* __restrict__ w1v = (const uint4*)w1s;
    swb[0][tid] = w1v[tid];               // weights k=0
    uint4 wldA = w1v[256 + tid];          // weights k=1 staged in regs
    uint4 wldB;
    __syncthreads();

    const uint4* __restrict__ yv = (const uint4*)y1;
    const int ib[3] = {(wv * 48 + m) * KK, (wv * 48 + 16 + m) * KK, (wv * 48 + 32 + m) * KK};

    uint4 ga[3][2];
#pragma unroll
    for (int p = 0; p < 2; p++)
#pragma unroll
        for (int t = 0; t < 3; t++) ga[t][p] = yv[s_idx[ib[t] + p] * 4 + g];

    f32x4 acc[3][4];
#pragma unroll
    for (int t = 0; t < 3; t++)
#pragma unroll
        for (int nt = 0; nt < 4; nt++) acc[t][nt] = (f32x4){0.f, 0.f, 0.f, 0.f};

#pragma unroll
    for (int k = 0; k < KK; k++) {
        const int b = k & 1;
        if (k + 2 < KK) {                 // issue weights k+2 (2-deep staging)
            if ((k & 1) == 0) wldB = w1v[(k + 2) * 256 + tid];
            else              wldA = w1v[(k + 2) * 256 + tid];
        }
        __builtin_amdgcn_sched_barrier(0);
        uint4 wb0 = swb[b][lane];
        uint4 wb1 = swb[b][64 + lane];
        uint4 wb2 = swb[b][128 + lane];
        uint4 wb3 = swb[b][192 + lane];
        __builtin_amdgcn_s_setprio(1);
#pragma unroll
        for (int t = 0; t < 3; t++) {
            bf16x8 a = as_bf8(ga[t][b]);
            acc[t][0] = MFMA16(a, as_bf8(wb0), acc[t][0], 0, 0, 0);
            acc[t][1] = MFMA16(a, as_bf8(wb1), acc[t][1], 0, 0, 0);
            acc[t][2] = MFMA16(a, as_bf8(wb2), acc[t][2], 0, 0, 0);
            acc[t][3] = MFMA16(a, as_bf8(wb3), acc[t][3], 0, 0, 0);
        }
        __builtin_amdgcn_s_setprio(0);
        __builtin_amdgcn_sched_barrier(0);
        if (k + 1 < KK)                   // write-late weights k+1 (loaded at iter k-1)
            swb[b ^ 1][tid] = ((k & 1) == 0) ? wldA : wldB;
        __builtin_amdgcn_sched_barrier(0);
        if (k + 2 < KK) {                 // refill freed slot with k+2's rows (stays in flight)
#pragma unroll
            for (int t = 0; t < 3; t++) ga[t][b] = yv[s_idx[ib[t] + k + 2] * 4 + g];
        }
        if (k + 1 < KK) {
            asm volatile("s_waitcnt lgkmcnt(0)" ::: "memory");
            __builtin_amdgcn_s_barrier();
            __builtin_amdgcn_sched_barrier(0);
        }
    }

    // epilogue: store bf16 pre-BN output
#pragma unroll
    for (int t = 0; t < 3; t++) {
        int rbase = blockRow0 + wv * 48 + t * 16 + g * 4;
#pragma unroll
        for (int reg = 0; reg < 4; reg++) {
            int r = rbase + reg;
            if (r < NVOX) {
                size_t bo = (size_t)r * COUT + m;
                out1[bo] = f2bf(acc[t][0][reg]);
                out1[bo + 16] = f2bf(acc[t][1][reg]);
                out1[bo + 32] = f2bf(acc[t][2][reg]);
                out1[bo + 48] = f2bf(acc[t][3][reg]);
            }
        }
    }

    // fused BN stats (f32, pre-rounding; OOB rows contribute exact zeros)
#pragma unroll
    for (int nt = 0; nt < 4; nt++) {
        float s = 0.f, q = 0.f;
#pragma unroll
        for (int t = 0; t < 3; t++)
#pragma unroll
            for (int reg = 0; reg < 4; reg++) {
                float v = acc[t][nt][reg];
                s += v; q += v * v;
            }
        s += __shfl_xor(s, 16); q += __shfl_xor(q, 16);
        s += __shfl_xor(s, 32); q += __shfl_xor(q, 32);
        if (g == 0) { atomicAdd(&s_sum[nt * 16 + m], s); atomicAdd(&s_sq[nt * 16 + m], q); }
    }
    __syncthreads();
    if (tid < COUT) {
        atomicAdd(&gsum[tid], s_sum[tid]);
        atomicAdd(&gsq[tid], s_sq[tid]);
    }
}

// ---------------- conv2: [N,64] -> [N,64] + fused residual, 32 rows/wave ----------------
// Same scheme as conv1: LDS weight dbuf + 2-deep register staging + write-before-refill.
// VGPR budget ~79 + 32 acc(AGPR) = 111 < 128 (4 waves/SIMD).
__global__ __launch_bounds__(256, 4) void conv2_kernel(const ushort* __restrict__ y2,
                                                       const int* __restrict__ nbr,
                                                       const ushort* __restrict__ w2s,
                                                       const float* __restrict__ x,
                                                       const ushort* __restrict__ wrs,
                                                       const float* __restrict__ bres,
                                                       float* __restrict__ out) {
    __shared__ int s_idx[128 * KK];       // 13824 B
    __shared__ uint4 swb[2][512];         // 16384 B: 8KB per k, double-buffered
    const int tid = threadIdx.x;
    const int lane = tid & 63, wv = tid >> 6;
    const int m = lane & 15, g = lane >> 4;

    const int blockRow0 = blockIdx.x * 128;
    const int gbase = blockRow0 * KK;
    const int glim = NVOX * KK;
    for (int i = tid; i < 128 * KK; i += 256) {
        int gi = gbase + i;
        int v = (gi < glim) ? nbr[gi] : NVOX;
        s_idx[i] = (int)min((unsigned)v, (unsigned)NVOX);
    }
    const uint4* __restrict__ w2v = (const uint4*)w2s;
    swb[0][tid] = w2v[tid];               // weights k=0 (8KB = 2 uint4/thread)
    swb[0][256 + tid] = w2v[256 + tid];
    uint4 wldA0 = w2v[512 + tid];         // weights k=1 staged in regs
    uint4 wldA1 = w2v[512 + 256 + tid];
    uint4 wldB0, wldB1;
    __syncthreads();

    const uint4* __restrict__ yv = (const uint4*)y2;
    const float4* __restrict__ xv = (const float4*)x;
    const uint4* __restrict__ wrv = (const uint4*)wrs;
    const int ib[2] = {(wv * 32 + m) * KK, (wv * 32 + 16 + m) * KK};

    uint4 ga[2][2][2];   // [tile][half][slot]
#pragma unroll
    for (int p = 0; p < 2; p++)
#pragma unroll
        for (int t = 0; t < 2; t++) {
            int idx = s_idx[ib[t] + p];
            ga[t][0][p] = yv[idx * 8 + g];
            ga[t][1][p] = yv[idx * 8 + 4 + g];
        }

    f32x4 acc[2][4];
#pragma unroll
    for (int t = 0; t < 2; t++)
#pragma unroll
        for (int nt = 0; nt < 4; nt++) acc[t][nt] = (f32x4){0.f, 0.f, 0.f, 0.f};

#pragma unroll
    for (int k = 0; k < KK; k++) {
        const int b = k & 1;
        if (k + 2 < KK) {                 // issue weights k+2 (2-deep staging)
            if ((k & 1) == 0) { wldB0 = w2v[(k + 2) * 512 + tid]; wldB1 = w2v[(k + 2) * 512 + 256 + tid]; }
            else              { wldA0 = w2v[(k + 2) * 512 + tid]; wldA1 = w2v[(k + 2) * 512 + 256 + tid]; }
        }
        __builtin_amdgcn_sched_barrier(0);
        // half 0: frags 0..3 (a0 side)
        uint4 wb0 = swb[b][lane];
        uint4 wb1 = swb[b][64 + lane];
        uint4 wb2 = swb[b][128 + lane];
        uint4 wb3 = swb[b][192 + lane];
        __builtin_amdgcn_s_setprio(1);
#pragma unroll
        for (int t = 0; t < 2; t++) {
            bf16x8 a0 = as_bf8(ga[t][0][b]);
            acc[t][0] = MFMA16(a0, as_bf8(wb0), acc[t][0], 0, 0, 0);
            acc[t][1] = MFMA16(a0, as_bf8(wb1), acc[t][1], 0, 0, 0);
            acc[t][2] = MFMA16(a0, as_bf8(wb2), acc[t][2], 0, 0, 0);
            acc[t][3] = MFMA16(a0, as_bf8(wb3), acc[t][3], 0, 0, 0);
        }
        __builtin_amdgcn_s_setprio(0);
        // half 1: frags 4..7 (a1 side)
        uint4 wb4 = swb[b][256 + lane];
        uint4 wb5 = swb[b][320 + lane];
        uint4 wb6 = swb[b][384 + lane];
        uint4 wb7 = swb[b][448 + lane];
        __builtin_amdgcn_s_setprio(1);
#pragma unroll
        for (int t = 0; t < 2; t++) {
            bf16x8 a1 = as_bf8(ga[t][1][b]);
            acc[t][0] = MFMA16(a1, as_bf8(wb4), acc[t][0], 0, 0, 0);
            acc[t][1] = MFMA16(a1, as_bf8(wb5), acc[t][1], 0, 0, 0);
            acc[t][2] = MFMA16(a1, as_bf8(wb6), acc[t][2], 0, 0, 0);
            acc[t][3] = MFMA16(a1, as_bf8(wb7), acc[t][3], 0, 0, 0);
        }
        __builtin_amdgcn_s_setprio(0);
        __builtin_amdgcn_sched_barrier(0);
        if (k + 1 < KK) {                 // write-late weights k+1 (loaded at iter k-1)
            if ((k & 1) == 0) { swb[b ^ 1][tid] = wldA0; swb[b ^ 1][256 + tid] = wldA1; }
            else              { swb[b ^ 1][tid] = wldB0; swb[b ^ 1][256 + tid] = wldB1; }
        }
        __builtin_amdgcn_sched_barrier(0);
        if (k + 2 < KK) {                 // refill freed slot with k+2's rows (stays in flight)
#pragma unroll
            for (int t = 0; t < 2; t++) {
                int idx = s_idx[ib[t] + k + 2];
                ga[t][0][b] = yv[idx * 8 + g];
                ga[t][1][b] = yv[idx * 8 + 4 + g];
            }
        }
        if (k + 1 < KK) {
            asm volatile("s_waitcnt lgkmcnt(0)" ::: "memory");
            __builtin_amdgcn_s_barrier();
            __builtin_amdgcn_sched_barrier(0);
        }
    }

    // residual GEMM: A = x (f32 -> bf16 on the fly, K=32), B = Wres
    uint4 wr0 = wrv[lane];
    uint4 wr1 = wrv[64 + lane];
    uint4 wr2 = wrv[128 + lane];
    uint4 wr3 = wrv[192 + lane];
#pragma unroll
    for (int t = 0; t < 2; t++) {
        int arow = blockRow0 + wv * 32 + t * 16 + m;
        bf16x8 ar;
        if (arow < NVOX) {
            float4 f0 = xv[(size_t)arow * 8 + g * 2];
            float4 f1 = xv[(size_t)arow * 8 + g * 2 + 1];
            ar = f8_to_bf8(f0, f1);
        } else {
            uint4 zz = {0u, 0u, 0u, 0u};
            ar = as_bf8(zz);
        }
        acc[t][0] = MFMA16(ar, as_bf8(wr0), acc[t][0], 0, 0, 0);
        acc[t][1] = MFMA16(ar, as_bf8(wr1), acc[t][1], 0, 0, 0);
        acc[t][2] = MFMA16(ar, as_bf8(wr2), acc[t][2], 0, 0, 0);
        acc[t][3] = MFMA16(ar, as_bf8(wr3), acc[t][3], 0, 0, 0);
    }

    float br0 = bres[m];
    float br1 = bres[16 + m];
    float br2 = bres[32 + m];
    float br3 = bres[48 + m];
#pragma unroll
    for (int t = 0; t < 2; t++) {
        int rbase = blockRow0 + wv * 32 + t * 16 + g * 4;
#pragma unroll
        for (int reg = 0; reg < 4; reg++) {
            int r = rbase + reg;
            if (r < NVOX) {
                size_t bo = (size_t)r * COUT + m;
                out[bo] = acc[t][0][reg] + br0;
                out[bo + 16] = acc[t][1][reg] + br1;
                out[bo + 32] = acc[t][2][reg] + br2;
                out[bo + 48] = acc[t][3][reg] + br3;
            }
        }
    }
}

extern "C" void kernel_launch(void* const* d_in, const int* in_sizes, int n_in,
                              void* d_out, int out_size, void* d_ws, size_t ws_size,
                              hipStream_t stream) {
    const float* x = (const float*)d_in[0];
    const int* nbr = (const int*)d_in[1];
    const float* W1 = (const float*)d_in[2];
    const float* W2 = (const float*)d_in[3];
    const float* Wres = (const float*)d_in[4];
    const float* bres = (const float*)d_in[5];
    const float* g1 = (const float*)d_in[6];
    const float* b1 = (const float*)d_in[7];
    const float* g2 = (const float*)d_in[8];
    const float* b2 = (const float*)d_in[9];
    float* out = (float*)d_out;

    // Workspace (~97 MB): y1 bf16 32MB, y2 bf16 64MB, weights/stats <0.5MB.
    // conv1's pre-BN bf16 output aliases the first 64MB of d_out (float, 128MB);
    // conv2 rewrites all of d_out afterwards.
    char* ws = (char*)d_ws;
    size_t off = 0;
    auto alloc = [&](size_t bytes) -> void* {
        void* p = ws + off;
        off = (off + bytes + 255) & ~(size_t)255;
        return p;
    };
    ushort* y1 = (ushort*)alloc((size_t)(NVOX + 1) * CIN * 2);    // sentinel row N = zeros
    ushort* y2 = (ushort*)alloc((size_t)(NVOX + 1) * COUT * 2);
    ushort* w1s = (ushort*)alloc(55296 * 2);
    ushort* w2s = (ushort*)alloc(110592 * 2);
    ushort* wrs = (ushort*)alloc(2048 * 2);
    float* stats = (float*)alloc(192 * 4);
    float* sum1 = stats, *sq1 = stats + 32, *sum2 = stats + 64, *sq2 = stats + 128;
    ushort* out1 = (ushort*)d_out;  // bf16 pre-BN conv1 output, first 64MB of d_out

    const float invN = 1.0f / (float)NVOX;
    const long long tot1 = (long long)NVOX * CIN / 4;   // float4/ushort4 groups
    const long long tot2 = (long long)NVOX * COUT / 4;
    const int conv1Grid = (NVOX + 191) / 192;
    const int conv2Grid = (NVOX + 127) / 128;

    hipLaunchKernelGGL(prep_kernel, dim3(658), dim3(256), 0, stream,
                       W1, W2, Wres, w1s, w2s, wrs, stats, y1, y2);
    hipLaunchKernelGGL(HIP_KERNEL_NAME(stats_kernel<32, float4>), dim3(1024), dim3(256), 0, stream,
                       (const float4*)x, tot1, sum1, sq1);
    hipLaunchKernelGGL(HIP_KERNEL_NAME(bn_relu_kernel<32, float4>), dim3(2048), dim3(256), 0, stream,
                       (const float4*)x, (ushort4*)y1, tot1, sum1, sq1, g1, b1, invN);
    hipLaunchKernelGGL(conv1_kernel, dim3(conv1Grid), dim3(256), 0, stream,
                       y1, nbr, w1s, out1, sum2, sq2);
    hipLaunchKernelGGL(HIP_KERNEL_NAME(bn_relu_kernel<64, ushort4>), dim3(2048), dim3(256), 0, stream,
                       (const ushort4*)out1, (ushort4*)y2, tot2, sum2, sq2, g2, b2, invN);
    hipLaunchKernelGGL(conv2_kernel, dim3(conv2Grid), dim3(256), 0, stream,
                       y2, nbr, w2s, x, wrs, bres, out);
    (void)in_sizes; (void)n_in; (void)out_size; (void)ws_size;
}